// Round 6
// baseline (103.403 us; speedup 1.0000x reference)
//
#include <hip/hip_runtime.h>

// DepthOffset: per (b, tap j, oy, ox) argmin_k |sample(j,k) - center|.
// sample(j,k) at (oy+4(jr-1)+2(kr-1), ox+4(jc-1)+2(kc-1)); two-stage zero pad:
//  stage1: tap origin OOB -> all 9 samples 0 -> diffs tie at |center| ->
//          argmin = first allowed k (code 0 for every tap type).
//  stage2: final position OOB -> sample 0 (per-element zeroing on load).
// masks: taps 1,7 allow only kc==1; taps 3,5 allow only kr==1.
// out[b,j] = (k/3-1)*2 ; out[b,9+j] = (k%3-1)*2   (int32)
//
// R6: barrier-free. Direct global float4 loads (4.9 MB input is L2-resident,
// 49x reuse), tournament argmin (min3+descending equality scan preserves
// jnp.argmin first-min tie-break), nontemporal int4 stores, 64-thread
// single-wave blocks for smooth tail drain.

#define BATCH 4
#define IH 480
#define IW 640
#define NG (IW / 4)  // 160 pixel-groups per row
#define NPIX ((long)BATCH * IH * IW)

typedef int iv4 __attribute__((ext_vector_type(4)));
typedef float fv4 __attribute__((ext_vector_type(4)));

__global__ __launch_bounds__(64) void depth_offset_kernel(
    const float* __restrict__ d, int* __restrict__ out) {
  int g = blockIdx.x * 64 + threadIdx.x;  // 307200 groups exactly
  int gx = g % NG;
  int t = g / NG;
  int oy = t % IH;
  int b = t / IH;
  int px = gx * 4;

  const float* __restrict__ db = d + (size_t)b * (IH * IW);

  // centers (row oy, cols px..px+3) — always in-bounds, aligned
  fv4 cen4 = *(const fv4*)(db + (size_t)oy * IW + px);
  float cen[4] = {cen4.x, cen4.y, cen4.z, cen4.w};

  // window cols [px-8, px+11]; xsafe -> whole span inside the row
  bool xsafe = (px >= 8) && (px <= IW - 12);

  float R0[20], R1[20], R2[20];
  // load window row i (image row oy+2i-6), zero outside image.
  // vec path allowed when allocation-safe (may cross rows; crossed lanes get
  // zeroed). Only the 4 global-corner threads fall to the scalar path.
#define LDG(R, i)                                                        \
  {                                                                      \
    int y = oy + 2 * (i) - 6;                                            \
    if ((unsigned)y < (unsigned)IH) {                                    \
      long a = ((long)(b * IH + y)) * IW + px - 8;                       \
      if (xsafe || (a >= 0 && a + 20 <= NPIX)) {                         \
        const fv4* rp = (const fv4*)(d + a);                             \
        *(fv4*)&R[0] = rp[0];                                            \
        *(fv4*)&R[4] = rp[1];                                            \
        *(fv4*)&R[8] = rp[2];                                            \
        *(fv4*)&R[12] = rp[3];                                           \
        *(fv4*)&R[16] = rp[4];                                           \
        if (!xsafe) {                                                    \
          _Pragma("unroll") for (int c = 0; c < 20; ++c) {               \
            int x = px + c - 8;                                          \
            if ((unsigned)x >= (unsigned)IW) R[c] = 0.f;                 \
          }                                                              \
        }                                                                \
      } else {                                                           \
        const float* ry_ = db + (size_t)y * IW;                          \
        _Pragma("unroll") for (int c = 0; c < 20; ++c) {                 \
          int x = px + c - 8;                                            \
          R[c] = ((unsigned)x < (unsigned)IW) ? ry_[x] : 0.f;            \
        }                                                                \
      }                                                                  \
    } else {                                                             \
      _Pragma("unroll") for (int c = 0; c < 20; ++c) R[c] = 0.f;         \
    }                                                                    \
  }

  const size_t plane = (size_t)IH * IW;
  int* obase = out + (size_t)b * 18 * plane + (size_t)oy * IW + px;
#define STORE2(J, oh, ow)                                               \
  {                                                                     \
    iv4 vh = {oh[0], oh[1], oh[2], oh[3]};                              \
    iv4 vw = {ow[0], ow[1], ow[2], ow[3]};                              \
    __builtin_nontemporal_store(vh, (iv4*)(obase + (size_t)(J)*plane)); \
    __builtin_nontemporal_store(vw,                                     \
                                (iv4*)(obase + (size_t)(9 + (J)) * plane)); \
  }

  bool yok0 = (oy >= 4), yok2 = (oy <= IH - 5);
  bool okTL[4], okTR[4], okBL[4], okBR[4], xokL[4], xokR[4];
#pragma unroll
  for (int p = 0; p < 4; ++p) {
    xokL[p] = (px + p >= 4);
    xokR[p] = (px + p <= IW - 5);
    okTL[p] = yok0 && xokL[p];
    okTR[p] = yok0 && xokR[p];
    okBL[p] = yok2 && xokL[p];
    okBR[p] = yok2 && xokR[p];
  }

  // full 9-candidate tap: rows RA,RB,RC (kr=0,1,2), local cols cb+2*kc.
  // code = (kr<<4)|kc; OOB fallback code 0 == first allowed k.
#define DO_TAP9(J, RA, RB, RC, CB0, OKP)            \
  {                                                 \
    int oh[4], ow[4];                               \
    _Pragma("unroll") for (int p = 0; p < 4; ++p) { \
      float cc = cen[p];                            \
      int cb = p + (CB0);                           \
      float a0 = fabsf(RA[cb] - cc);                \
      float a1 = fabsf(RA[cb + 2] - cc);            \
      float a2 = fabsf(RA[cb + 4] - cc);            \
      float a3 = fabsf(RB[cb] - cc);                \
      float a4 = fabsf(RB[cb + 2] - cc);            \
      float a5 = fabsf(RB[cb + 4] - cc);            \
      float a6 = fabsf(RC[cb] - cc);                \
      float a7 = fabsf(RC[cb + 2] - cc);            \
      float a8 = fabsf(RC[cb + 4] - cc);            \
      float m012 = fminf(fminf(a0, a1), a2);        \
      float m345 = fminf(fminf(a3, a4), a5);        \
      float m678 = fminf(fminf(a6, a7), a8);        \
      float m = fminf(fminf(m012, m345), m678);     \
      int code = 34;                                \
      code = (a7 == m) ? 33 : code;                 \
      code = (a6 == m) ? 32 : code;                 \
      code = (a5 == m) ? 18 : code;                 \
      code = (a4 == m) ? 17 : code;                 \
      code = (a3 == m) ? 16 : code;                 \
      code = (a2 == m) ? 2 : code;                  \
      code = (a1 == m) ? 1 : code;                  \
      code = (a0 == m) ? 0 : code;                  \
      code = (OKP) ? code : 0;                      \
      oh[p] = ((code >> 4) * 2) - 2;                \
      ow[p] = ((code & 15) * 2) - 2;                \
    }                                               \
    STORE2(J, oh, ow)                               \
  }

  // vertical tap (j=1,7): only kc==1 -> local col p+8; code = kr.
#define DO_TAPV(J, RA, RB, RC, OKE)                 \
  {                                                 \
    int oh[4], ow[4];                               \
    _Pragma("unroll") for (int p = 0; p < 4; ++p) { \
      float cc = cen[p];                            \
      int cb = p + 8;                                \
      float a0 = fabsf(RA[cb] - cc);                \
      float a1 = fabsf(RB[cb] - cc);                \
      float a2 = fabsf(RC[cb] - cc);                \
      float m = fminf(fminf(a0, a1), a2);           \
      int code = 2;                                 \
      code = (a1 == m) ? 1 : code;                  \
      code = (a0 == m) ? 0 : code;                  \
      code = (OKE) ? code : 0;                      \
      oh[p] = code * 2 - 2;                         \
      ow[p] = 0;                                    \
    }                                               \
    STORE2(J, oh, ow)                               \
  }

  // horizontal tap (j=3,5): only kr==1 -> center row R; code = kc.
#define DO_TAPH(J, R, CB0, OKP)                     \
  {                                                 \
    int oh[4], ow[4];                               \
    _Pragma("unroll") for (int p = 0; p < 4; ++p) { \
      float cc = cen[p];                            \
      int cb = p + (CB0);                           \
      float a0 = fabsf(R[cb] - cc);                 \
      float a1 = fabsf(R[cb + 2] - cc);             \
      float a2 = fabsf(R[cb + 4] - cc);             \
      float m = fminf(fminf(a0, a1), a2);           \
      int code = 2;                                 \
      code = (a1 == m) ? 1 : code;                  \
      code = (a0 == m) ? 0 : code;                  \
      code = (OKP) ? code : 0;                      \
      oh[p] = 0;                                    \
      ow[p] = code * 2 - 2;                         \
    }                                               \
    STORE2(J, oh, ow)                               \
  }

  // Phase A: taps jr=0 use window rows 0,1,2
  LDG(R0, 0)
  LDG(R1, 1)
  LDG(R2, 2)
  DO_TAP9(0, R0, R1, R2, 2, okTL[p])
  DO_TAPV(1, R0, R1, R2, yok0)
  DO_TAP9(2, R0, R1, R2, 10, okTR[p])
  // Phase B: taps jr=1 use rows 2,3,4 -> R2(w2), reload R0<-w3, R1<-w4
  LDG(R0, 3)
  LDG(R1, 4)
  DO_TAPH(3, R0, 2, xokL[p])
  DO_TAP9(4, R2, R0, R1, 6, true)
  DO_TAPH(5, R0, 10, xokR[p])
  // Phase C: taps jr=2 use rows 4,5,6 -> R1(w4), reload R2<-w5, R0<-w6
  LDG(R2, 5)
  LDG(R0, 6)
  DO_TAP9(6, R1, R2, R0, 2, okBL[p])
  DO_TAPV(7, R1, R2, R0, yok2)
  DO_TAP9(8, R1, R2, R0, 10, okBR[p])
}

extern "C" void kernel_launch(void* const* d_in, const int* in_sizes, int n_in,
                              void* d_out, int out_size, void* d_ws, size_t ws_size,
                              hipStream_t stream) {
  const float* depth = (const float*)d_in[0];
  int* out = (int*)d_out;
  const int nthreads = BATCH * IH * NG;  // 307200 = 4800 blocks x 64
  depth_offset_kernel<<<nthreads / 64, 64, 0, stream>>>(depth, out);
}